// Round 7
// baseline (475.458 us; speedup 1.0000x reference)
//
#include <hip/hip_runtime.h>
#include <math.h>

#define NN 100000     // nodes
#define NE 1600000    // edges
#define D  128        // feature dim
#define NW 64         // u32 words per row (D/2 packed bf16x2)
#define NL 3          // layers

typedef unsigned int u32;
typedef __attribute__((ext_vector_type(8))) short bf16x8;
typedef __attribute__((ext_vector_type(4))) float f32x4;

// ---- packed bf16x2 helpers (RNE) ----
__device__ inline float blo(u32 v) { return __uint_as_float(v << 16); }
__device__ inline float bhi(u32 v) { return __uint_as_float(v & 0xffff0000u); }
__device__ inline u32 bpack(float x, float y) {
  u32 xb = __float_as_uint(x), yb = __float_as_uint(y);
  xb = (xb + 0x7fffu + ((xb >> 16) & 1u)) >> 16;
  yb = (yb + 0x7fffu + ((yb >> 16) & 1u)) & 0xffff0000u;
  return xb | yb;
}

// ---------------- degree count: 8 edges/thread, fire-and-forget atomics ------

__global__ __launch_bounds__(256) void k_count(const int* __restrict__ dstv,
                                               unsigned* __restrict__ deg) {
  const int base = (blockIdx.x * 256 + threadIdx.x) * 8;
  if (base + 8 <= NE) {
    const int4 d0 = *(const int4*)(dstv + base);
    const int4 d1 = *(const int4*)(dstv + base + 4);
    atomicAdd(&deg[d0.x], 1u); atomicAdd(&deg[d0.y], 1u);
    atomicAdd(&deg[d0.z], 1u); atomicAdd(&deg[d0.w], 1u);
    atomicAdd(&deg[d1.x], 1u); atomicAdd(&deg[d1.y], 1u);
    atomicAdd(&deg[d1.z], 1u); atomicAdd(&deg[d1.w], 1u);
  } else {
    for (int i = base; i < NE; ++i) atomicAdd(&deg[dstv[i]], 1u);
  }
}

__global__ __launch_bounds__(256) void k_dinv(const unsigned* __restrict__ deg,
                                              float* __restrict__ dinv) {
  int i = blockIdx.x * 256 + threadIdx.x;
  if (i < NN) dinv[i] = 1.0f / sqrtf((float)(deg[i] + 1u));
}

// ---------------- x -> packed bf16 ----------------

__global__ __launch_bounds__(256) void k_cvt(const float* __restrict__ x,
                                             u32* __restrict__ xb) {
  int i = blockIdx.x * 256 + threadIdx.x;
  if (i < NN * NW) {
    const float2 v = *(const float2*)&x[(size_t)i * 2];
    xb[i] = bpack(v.x, v.y);
  }
}

// ---------------- W (f32 [k][n]) -> bf16 W^T [n][k], packed u32 ----------------

__global__ __launch_bounds__(256) void k_wcvt(const float* __restrict__ Ws,
                                              u32* __restrict__ Wtb) {
  int i = blockIdx.x * 256 + threadIdx.x;   // l*8192 + n*64 + kw
  if (i >= NL * 128 * 64) return;
  const int l = i >> 13, rem = i & 8191, n = rem >> 6, kw = rem & 63;
  const float* Wp = Ws + l * (D * D);
  Wtb[i] = bpack(Wp[(2 * kw) * D + n], Wp[(2 * kw + 1) * D + n]);
}

// ---------------- CSR build: 3-stage exclusive scan ----------------

__global__ __launch_bounds__(256) void k_scan1(const unsigned* __restrict__ deg,
                                               unsigned* __restrict__ bsum) {
  __shared__ unsigned s[256];
  int t = threadIdx.x;
  int i = blockIdx.x * 256 + t;
  s[t] = (i < NN) ? deg[i] : 0u;
  __syncthreads();
  for (int off = 128; off > 0; off >>= 1) {
    if (t < off) s[t] += s[t + off];
    __syncthreads();
  }
  if (t == 0) bsum[blockIdx.x] = s[0];
}

__global__ __launch_bounds__(512) void k_scan2(const unsigned* __restrict__ bsum,
                                               unsigned* __restrict__ boff, int nb) {
  __shared__ unsigned s[512];
  int t = threadIdx.x;
  unsigned v = (t < nb) ? bsum[t] : 0u;
  s[t] = v;
  __syncthreads();
  for (int off = 1; off < 512; off <<= 1) {
    unsigned x = (t >= off) ? s[t - off] : 0u;
    __syncthreads();
    s[t] += x;
    __syncthreads();
  }
  if (t < nb) boff[t] = s[t] - v;   // exclusive
}

// scan3 also seeds fillcnt = rowptr so k_fill's atomic needs no rowptr load.
__global__ __launch_bounds__(256) void k_scan3(const unsigned* __restrict__ deg,
                                               const unsigned* __restrict__ boff,
                                               unsigned* __restrict__ rowptr,
                                               unsigned* __restrict__ fillcnt) {
  __shared__ unsigned s[256];
  int t = threadIdx.x;
  int i = blockIdx.x * 256 + t;
  unsigned v = (i < NN) ? deg[i] : 0u;
  s[t] = v;
  __syncthreads();
  for (int off = 1; off < 256; off <<= 1) {
    unsigned x = (t >= off) ? s[t - off] : 0u;
    __syncthreads();
    s[t] += x;
    __syncthreads();
  }
  unsigned excl = s[t] - v + boff[blockIdx.x];
  if (i <= NN) rowptr[i] = excl;    // i==NN lands exactly on total == NE
  if (i < NN)  fillcnt[i] = excl;
}

// ---------------- CSR fill: 1 edge/thread, 4B scatter (col only) -------------

__global__ __launch_bounds__(256) void k_fill(const int* __restrict__ srcv,
                                              const int* __restrict__ dstv,
                                              unsigned* __restrict__ fillcnt,  // = rowptr seed
                                              int* __restrict__ colv) {
  const int i = blockIdx.x * 256 + threadIdx.x;
  if (i >= NE) return;
  const int d = dstv[i];
  const unsigned pos = atomicAdd(&fillcnt[d], 1u);
  colv[pos] = srcv[i];
}

// ---------------- GEMM: hw = h @ W  (bf16 MFMA, W^T in swizzled LDS) ----------
// 512 threads (8 waves), 128 rows/block. Per wave: 16 rows x 128 cols via
// 32x mfma_f32_16x16x32_bf16. A frag: row=lane&15, k=(lane>>4)*8+j (m89/m91
// layout). B frag from LDS W^T[n][k], XOR-swizzled (byte ^= (n&7)<<4) on both
// write and read (rule #21). D: col=lane&15, row=(lane>>4)*4+reg. Epilogue
// packs col pairs via shfl_xor(1) into bf16x2 words.

__global__ __launch_bounds__(512, 4) void k_gemm(const u32* __restrict__ Ab,
                                                 const u32* __restrict__ Wtb,
                                                 u32* __restrict__ Bb) {
  __shared__ u32 Wl[128 * 64];   // 32 KB
  const int t = threadIdx.x;
#pragma unroll
  for (int i = 0; i < 4; ++i) {
    const int idx = (t + i * 512) * 4;          // u32 index of a 16B chunk
    const uint4 v = *(const uint4*)(Wtb + idx);
    const int byte = idx * 4;
    const int sw = byte ^ (((byte >> 8) & 7) << 4);
    *(uint4*)((char*)Wl + sw) = v;
  }
  __syncthreads();

  const int wave = t >> 6, lane = t & 63;
  const int hi = lane >> 4;                     // 0..3
  const int lo = lane & 15;
  int row = blockIdx.x * 128 + wave * 16 + lo;
  const int rowc = row < NN ? row : NN - 1;     // clamp reads, guard writes

  bf16x8 af[4];
#pragma unroll
  for (int ks = 0; ks < 4; ++ks)
    af[ks] = *(const bf16x8*)(Ab + (size_t)rowc * NW + ks * 16 + hi * 4);

  f32x4 acc[8];
#pragma unroll
  for (int ct = 0; ct < 8; ++ct) acc[ct] = (f32x4){0.f, 0.f, 0.f, 0.f};

#pragma unroll
  for (int ks = 0; ks < 4; ++ks) {
#pragma unroll
    for (int ct = 0; ct < 8; ++ct) {
      const int n = ct * 16 + lo;
      const int addr = (n * 256 + ks * 64 + hi * 16) ^ ((n & 7) << 4);
      const bf16x8 bf = *(const bf16x8*)((const char*)Wl + addr);
      acc[ct] = __builtin_amdgcn_mfma_f32_16x16x32_bf16(af[ks], bf, acc[ct], 0, 0, 0);
    }
  }

  const int rbase = blockIdx.x * 128 + wave * 16 + hi * 4;
  const bool even = (lane & 1) == 0;
  const int wcol = lo >> 1;                     // word index within ct's 8
#pragma unroll
  for (int ct = 0; ct < 8; ++ct) {
    float p0 = __shfl_xor(acc[ct][0], 1, 64);
    float p1 = __shfl_xor(acc[ct][1], 1, 64);
    float p2 = __shfl_xor(acc[ct][2], 1, 64);
    float p3 = __shfl_xor(acc[ct][3], 1, 64);
    const u32 wA = even ? bpack(acc[ct][0], p0) : bpack(p2, acc[ct][2]);
    const u32 wB = even ? bpack(acc[ct][1], p1) : bpack(p3, acc[ct][3]);
    const int rA = rbase + (even ? 0 : 2);
    if (rA < NN)     Bb[(size_t)rA * NW + ct * 8 + wcol] = wA;
    if (rA + 1 < NN) Bb[(size_t)(rA + 1) * NW + ct * 8 + wcol] = wB;
  }
}

// ---------------- Aggregation: one wave per node, lane-cooperative edge load ----
// Lanes 0..min(deg,64) load colv[s+lane] (coalesced) + dinv[src] (gather),
// then per-edge broadcast via shfl, 8-deep batched row gathers. deg>64 tail
// (astronomically rare for this graph) falls back to broadcast loads.

__global__ __launch_bounds__(256) void k_agg(const u32* __restrict__ hwb,
                                             const int* __restrict__ colv,
                                             const unsigned* __restrict__ rowptr,
                                             const float* __restrict__ dinv,
                                             const float* __restrict__ bias,
                                             u32* __restrict__ hob) {
  const int widt = (blockIdx.x * 256 + threadIdx.x) >> 6;
  if (widt >= NN) return;
  const int wid = __builtin_amdgcn_readfirstlane(widt);
  const int lane = threadIdx.x & 63;

  const float di = dinv[wid];
  const u32 sv = hwb[(size_t)wid * NW + lane];
  float ax = blo(sv) * di * di, ay = bhi(sv) * di * di;

  const unsigned s = rowptr[wid], e = rowptr[wid + 1];
  const int deg = (int)(e - s);
  const int nl = deg < 64 ? deg : 64;

  // cooperative load of up to 64 edges for this node
  int   srcl = wid;
  float wl = 0.f;
  if (lane < nl) {
    srcl = colv[s + lane];
    wl = dinv[srcl] * di;
  }

  int q = 0;
  for (; q + 8 <= nl; q += 8) {
    int sq[8]; float wq[8]; u32 uq[8];
#pragma unroll
    for (int k = 0; k < 8; ++k) {
      sq[k] = __shfl(srcl, q + k, 64);
      wq[k] = __shfl(wl,   q + k, 64);
    }
#pragma unroll
    for (int k = 0; k < 8; ++k) uq[k] = hwb[(size_t)sq[k] * NW + lane];
#pragma unroll
    for (int k = 0; k < 8; ++k) {
      ax = fmaf(wq[k], blo(uq[k]), ax);
      ay = fmaf(wq[k], bhi(uq[k]), ay);
    }
  }
  for (; q < nl; ++q) {
    const int   sq = __shfl(srcl, q, 64);
    const float wq = __shfl(wl,   q, 64);
    const u32 u = hwb[(size_t)sq * NW + lane];
    ax = fmaf(wq, blo(u), ax);
    ay = fmaf(wq, bhi(u), ay);
  }
  // rare tail: degree > 64
  for (unsigned j = s + (unsigned)nl; j < e; ++j) {
    const int src = colv[j];                 // wave-uniform
    const float w = dinv[src] * di;
    const u32 u = hwb[(size_t)src * NW + lane];
    ax = fmaf(w, blo(u), ax);
    ay = fmaf(w, bhi(u), ay);
  }

  const float2 b = *(const float2*)&bias[lane * 2];
  ax += b.x; ay += b.y;
  ax = ax > 0.f ? ax : 0.f;
  ay = ay > 0.f ? ay : 0.f;
  hob[(size_t)wid * NW + lane] = bpack(ax, ay);
}

// ---------------- Head GEMV: out = h @ head_W + head_b ----------------

__global__ __launch_bounds__(256) void k_head(const u32* __restrict__ hb,
                                              const float* __restrict__ hW,
                                              const float* __restrict__ hbv,
                                              float* __restrict__ out) {
  const int widt = (blockIdx.x * 256 + threadIdx.x) >> 6;
  if (widt >= NN) return;
  const int wid = __builtin_amdgcn_readfirstlane(widt);
  const int lane = threadIdx.x & 63;
  const u32 v = hb[(size_t)wid * NW + lane];
  const float2 w = *(const float2*)&hW[lane * 2];
  float sum = blo(v) * w.x + bhi(v) * w.y;
#pragma unroll
  for (int off = 32; off > 0; off >>= 1) sum += __shfl_down(sum, off, 64);
  if (lane == 0) out[wid] = sum + hbv[0];
}

// ---------------- launch ----------------

extern "C" void kernel_launch(void* const* d_in, const int* in_sizes, int n_in,
                              void* d_out, int out_size, void* d_ws, size_t ws_size,
                              hipStream_t stream) {
  const float* x   = (const float*)d_in[0];
  const int*   ei  = (const int*)d_in[1];
  const float* Ws  = (const float*)d_in[2];
  const float* bs  = (const float*)d_in[3];
  const float* hW  = (const float*)d_in[4];
  const float* hb  = (const float*)d_in[5];
  float* out = (float*)d_out;

  char* w = (char*)d_ws;
  u32*      bufA    = (u32*)w;      w += (size_t)NN * NW * 4;      // 25.6 MB (h)
  u32*      bufB    = (u32*)w;      w += (size_t)NN * NW * 4;      // 25.6 MB (hw)
  int*      colv    = (int*)w;      w += (size_t)NE * 4;           // 6.4 MB
  u32*      Wtb     = (u32*)w;      w += (size_t)NL * 128 * 64 * 4; // 96 KB
  unsigned* rowptr  = (unsigned*)w; w += (size_t)(NN + 16) * 4;
  unsigned* deg     = (unsigned*)w; w += (size_t)NN * 4;
  unsigned* fillcnt = (unsigned*)w; w += (size_t)NN * 4;
  float*    dinv    = (float*)w;    w += (size_t)NN * 4;
  unsigned* bsum    = (unsigned*)w; w += 512 * 4;
  unsigned* boff    = (unsigned*)w; w += 512 * 4;

  const int* srcv = ei;
  const int* dstv = ei + NE;

  hipMemsetAsync(deg, 0, (size_t)NN * 4, stream);

  const int NB = (NN + 255) / 256;          // 391
  const int NB8 = (NE / 8 + 255) / 256;     // 782

  k_count<<<NB8, 256, 0, stream>>>(dstv, deg);
  k_dinv <<<NB, 256, 0, stream>>>(deg, dinv);
  k_cvt  <<<(NN * NW + 255) / 256, 256, 0, stream>>>(x, bufA);
  k_wcvt <<<(NL * 128 * 64 + 255) / 256, 256, 0, stream>>>(Ws, Wtb);
  k_scan1<<<NB, 256, 0, stream>>>(deg, bsum);
  k_scan2<<<1, 512, 0, stream>>>(bsum, boff, NB);
  k_scan3<<<NB, 256, 0, stream>>>(deg, boff, rowptr, fillcnt);
  k_fill <<<(NE + 255) / 256, 256, 0, stream>>>(srcv, dstv, fillcnt, colv);

  for (int l = 0; l < NL; ++l) {
    k_gemm<<<(NN + 127) / 128, 512, 0, stream>>>(bufA, Wtb + (size_t)l * 128 * 64, bufB);
    k_agg <<<(NN + 3) / 4, 256, 0, stream>>>(bufB, colv, rowptr, dinv,
                                             bs + (size_t)l * D, bufA);
  }

  k_head<<<(NN + 3) / 4, 256, 0, stream>>>(bufA, hW, hb, out);
}

// Round 8
// 311.195 us; speedup vs baseline: 1.5278x; 1.5278x over previous
//
#include <hip/hip_runtime.h>
#include <math.h>

#define NN 100000     // nodes
#define NE 1600000    // edges
#define D  128        // feature dim
#define NW 64         // u32 words per row (D/2 packed bf16x2)
#define NL 3          // layers
#define NCH 256       // edge chunks (NE % NCH == 0 -> CH = 6250)
#define CH  (NE / NCH)
#define NBK 391       // dst buckets: dst >> 8, (NN+255)>>8
#define CAP 6016      // LDS colv staging capacity per bucket (mean 4096, sd 64)

typedef unsigned int u32;
typedef __attribute__((ext_vector_type(8))) short bf16x8;
typedef __attribute__((ext_vector_type(4))) float f32x4;

// ---- packed bf16x2 helpers (RNE) ----
__device__ inline float blo(u32 v) { return __uint_as_float(v << 16); }
__device__ inline float bhi(u32 v) { return __uint_as_float(v & 0xffff0000u); }
__device__ inline u32 bpack(float x, float y) {
  u32 xb = __float_as_uint(x), yb = __float_as_uint(y);
  xb = (xb + 0x7fffu + ((xb >> 16) & 1u)) >> 16;
  yb = (yb + 0x7fffu + ((yb >> 16) & 1u)) & 0xffff0000u;
  return xb | yb;
}

// ================= bucketed CSR build (no global scatter) =================

// Phase A: per-chunk histogram of dst>>8 into LDS, coalesced dump.
__global__ __launch_bounds__(256) void k_hist(const int* __restrict__ dstv,
                                              u32* __restrict__ hist) {
  __shared__ u32 h[NBK];
  const int t = threadIdx.x, c = blockIdx.x;
  for (int b = t; b < NBK; b += 256) h[b] = 0u;
  __syncthreads();
  const int base = c * CH;
  for (int i = t; i < CH; i += 256)
    atomicAdd(&h[dstv[base + i] >> 8], 1u);
  __syncthreads();
  for (int b = t; b < NBK; b += 256) hist[b * NCH + c] = h[b];
}

// Phase B1: per-bucket totals (one block per bucket, coalesced row read).
__global__ __launch_bounds__(256) void k_btot(const u32* __restrict__ hist,
                                              u32* __restrict__ btot) {
  __shared__ u32 s[256];
  const int b = blockIdx.x, t = threadIdx.x;
  s[t] = hist[b * NCH + t];
  __syncthreads();
  for (int off = 128; off > 0; off >>= 1) {
    if (t < off) s[t] += s[t + off];
    __syncthreads();
  }
  if (t == 0) btot[b] = s[0];
}

// Phase B2: exclusive scan of 391 bucket totals.
__global__ __launch_bounds__(512) void k_bscan(const u32* __restrict__ btot,
                                               u32* __restrict__ bkbase) {
  __shared__ u32 s[512];
  const int t = threadIdx.x;
  const u32 v = (t < NBK) ? btot[t] : 0u;
  s[t] = v;
  __syncthreads();
  for (int off = 1; off < 512; off <<= 1) {
    const u32 x = (t >= off) ? s[t - off] : 0u;
    __syncthreads();
    s[t] += x;
    __syncthreads();
  }
  if (t < NBK) bkbase[t] = s[t] - v;
  if (t == 0) bkbase[NBK] = NE;
}

// Phase B3: per-bucket exclusive scan over chunk counts -> absolute offsets.
__global__ __launch_bounds__(256) void k_cscan(const u32* __restrict__ bkbase,
                                               u32* __restrict__ hist) {
  __shared__ u32 s[256];
  const int b = blockIdx.x, t = threadIdx.x;
  const u32 v = hist[b * NCH + t];
  s[t] = v;
  __syncthreads();
  for (int off = 1; off < 256; off <<= 1) {
    const u32 x = (t >= off) ? s[t - off] : 0u;
    __syncthreads();
    s[t] += x;
    __syncthreads();
  }
  hist[b * NCH + t] = bkbase[b] + s[t] - v;
}

// Phase C: scatter edges into bucket-major order. LDS cursors -> each block's
// writes per bucket form a contiguous ~64B run (no line ping-pong).
__global__ __launch_bounds__(256) void k_scatter(const int* __restrict__ srcv,
                                                 const int* __restrict__ dstv,
                                                 const u32* __restrict__ off,
                                                 u32* __restrict__ ebuf) {
  __shared__ u32 cur[NBK];
  const int t = threadIdx.x, c = blockIdx.x;
  for (int b = t; b < NBK; b += 256) cur[b] = off[b * NCH + c];
  __syncthreads();
  const int base = c * CH;
  for (int i = t; i < CH; i += 256) {
    const int d = dstv[base + i], s = srcv[base + i];
    const u32 p = atomicAdd(&cur[d >> 8], 1u);
    ebuf[p] = (u32)s | ((u32)(d & 255) << 17);   // src:17b | dst_local:8b
  }
}

// Phase D: one block per bucket. LDS node-histogram + scan -> rowptr + dinv;
// LDS scatter -> coalesced colv write.
__global__ __launch_bounds__(256) void k_build(const u32* __restrict__ ebuf,
                                               const u32* __restrict__ bkbase,
                                               int* __restrict__ colv,
                                               unsigned* __restrict__ rowptr,
                                               float* __restrict__ dinv) {
  __shared__ u32 loc[256];
  __shared__ u32 curn[256];
  __shared__ u32 hl[256];
  __shared__ u32 cbuf[CAP];
  const int b = blockIdx.x, t = threadIdx.x;
  const u32 e0 = bkbase[b], e1 = bkbase[b + 1];
  const int cnt = (int)(e1 - e0);
  const int node = (b << 8) + t;

  hl[t] = 0u;
  __syncthreads();
  for (int i = t; i < cnt; i += 256)
    atomicAdd(&hl[(ebuf[e0 + i] >> 17) & 255u], 1u);
  __syncthreads();
  const u32 v = hl[t];
  loc[t] = v;
  __syncthreads();
  for (int off = 1; off < 256; off <<= 1) {
    const u32 x = (t >= off) ? loc[t - off] : 0u;
    __syncthreads();
    loc[t] += x;
    __syncthreads();
  }
  const u32 excl = loc[t] - v;
  if (node < NN) {
    rowptr[node] = e0 + excl;
    dinv[node] = rsqrtf((float)(v + 1u));     // in-degree + self-loop
  }
  if (b == NBK - 1 && t == 0) rowptr[NN] = NE;
  curn[t] = excl;
  __syncthreads();

  if (cnt <= CAP) {
    for (int i = t; i < cnt; i += 256) {
      const u32 e = ebuf[e0 + i];
      const u32 p = atomicAdd(&curn[(e >> 17) & 255u], 1u);
      cbuf[p] = e & 0x1FFFFu;
    }
    __syncthreads();
    for (int i = t; i < cnt; i += 256) colv[e0 + i] = (int)cbuf[i];
  } else {      // statistically unreachable safety net
    for (int i = t; i < cnt; i += 256) {
      const u32 e = ebuf[e0 + i];
      const u32 p = atomicAdd(&curn[(e >> 17) & 255u], 1u);
      colv[e0 + p] = (int)(e & 0x1FFFFu);
    }
  }
}

// ---------------- x -> packed bf16 ----------------

__global__ __launch_bounds__(256) void k_cvt(const float* __restrict__ x,
                                             u32* __restrict__ xb) {
  int i = blockIdx.x * 256 + threadIdx.x;
  if (i < NN * NW) {
    const float2 v = *(const float2*)&x[(size_t)i * 2];
    xb[i] = bpack(v.x, v.y);
  }
}

// ---------------- W (f32 [k][n]) -> bf16 W^T [n][k], packed u32 ----------------

__global__ __launch_bounds__(256) void k_wcvt(const float* __restrict__ Ws,
                                              u32* __restrict__ Wtb) {
  int i = blockIdx.x * 256 + threadIdx.x;   // l*8192 + n*64 + kw
  if (i >= NL * 128 * 64) return;
  const int l = i >> 13, rem = i & 8191, n = rem >> 6, kw = rem & 63;
  const float* Wp = Ws + l * (D * D);
  Wtb[i] = bpack(Wp[(2 * kw) * D + n], Wp[(2 * kw + 1) * D + n]);
}

// ---------------- GEMM: hw = h @ W  (bf16 MFMA, W^T in swizzled LDS) ----------

__global__ __launch_bounds__(512, 4) void k_gemm(const u32* __restrict__ Ab,
                                                 const u32* __restrict__ Wtb,
                                                 u32* __restrict__ Bb) {
  __shared__ u32 Wl[128 * 64];   // 32 KB
  const int t = threadIdx.x;
#pragma unroll
  for (int i = 0; i < 4; ++i) {
    const int idx = (t + i * 512) * 4;          // u32 index of a 16B chunk
    const uint4 v = *(const uint4*)(Wtb + idx);
    const int byte = idx * 4;
    const int sw = byte ^ (((byte >> 8) & 7) << 4);
    *(uint4*)((char*)Wl + sw) = v;
  }
  __syncthreads();

  const int wave = t >> 6, lane = t & 63;
  const int hi = lane >> 4;                     // 0..3
  const int lo = lane & 15;
  int row = blockIdx.x * 128 + wave * 16 + lo;
  const int rowc = row < NN ? row : NN - 1;     // clamp reads, guard writes

  bf16x8 af[4];
#pragma unroll
  for (int ks = 0; ks < 4; ++ks)
    af[ks] = *(const bf16x8*)(Ab + (size_t)rowc * NW + ks * 16 + hi * 4);

  f32x4 acc[8];
#pragma unroll
  for (int ct = 0; ct < 8; ++ct) acc[ct] = (f32x4){0.f, 0.f, 0.f, 0.f};

#pragma unroll
  for (int ks = 0; ks < 4; ++ks) {
#pragma unroll
    for (int ct = 0; ct < 8; ++ct) {
      const int n = ct * 16 + lo;
      const int addr = (n * 256 + ks * 64 + hi * 16) ^ ((n & 7) << 4);
      const bf16x8 bf = *(const bf16x8*)((const char*)Wl + addr);
      acc[ct] = __builtin_amdgcn_mfma_f32_16x16x32_bf16(af[ks], bf, acc[ct], 0, 0, 0);
    }
  }

  const int rbase = blockIdx.x * 128 + wave * 16 + hi * 4;
  const bool even = (lane & 1) == 0;
  const int wcol = lo >> 1;                     // word index within ct's 8
#pragma unroll
  for (int ct = 0; ct < 8; ++ct) {
    float p0 = __shfl_xor(acc[ct][0], 1, 64);
    float p1 = __shfl_xor(acc[ct][1], 1, 64);
    float p2 = __shfl_xor(acc[ct][2], 1, 64);
    float p3 = __shfl_xor(acc[ct][3], 1, 64);
    const u32 wA = even ? bpack(acc[ct][0], p0) : bpack(p2, acc[ct][2]);
    const u32 wB = even ? bpack(acc[ct][1], p1) : bpack(p3, acc[ct][3]);
    const int rA = rbase + (even ? 0 : 2);
    if (rA < NN)     Bb[(size_t)rA * NW + ct * 8 + wcol] = wA;
    if (rA + 1 < NN) Bb[(size_t)(rA + 1) * NW + ct * 8 + wcol] = wB;
  }
}

// ---------------- Aggregation: one wave per node, lane-cooperative edge load ----

__global__ __launch_bounds__(256) void k_agg(const u32* __restrict__ hwb,
                                             const int* __restrict__ colv,
                                             const unsigned* __restrict__ rowptr,
                                             const float* __restrict__ dinv,
                                             const float* __restrict__ bias,
                                             u32* __restrict__ hob) {
  const int widt = (blockIdx.x * 256 + threadIdx.x) >> 6;
  if (widt >= NN) return;
  const int wid = __builtin_amdgcn_readfirstlane(widt);
  const int lane = threadIdx.x & 63;

  const float di = dinv[wid];
  const u32 sv = hwb[(size_t)wid * NW + lane];
  float ax = blo(sv) * di * di, ay = bhi(sv) * di * di;

  const unsigned s = rowptr[wid], e = rowptr[wid + 1];
  const int deg = (int)(e - s);
  const int nl = deg < 64 ? deg : 64;

  // cooperative load of up to 64 edges for this node
  int   srcl = wid;
  float wl = 0.f;
  if (lane < nl) {
    srcl = colv[s + lane];
    wl = dinv[srcl] * di;
  }

  int q = 0;
  for (; q + 8 <= nl; q += 8) {
    int sq[8]; float wq[8]; u32 uq[8];
#pragma unroll
    for (int k = 0; k < 8; ++k) {
      sq[k] = __shfl(srcl, q + k, 64);
      wq[k] = __shfl(wl,   q + k, 64);
    }
#pragma unroll
    for (int k = 0; k < 8; ++k) uq[k] = hwb[(size_t)sq[k] * NW + lane];
#pragma unroll
    for (int k = 0; k < 8; ++k) {
      ax = fmaf(wq[k], blo(uq[k]), ax);
      ay = fmaf(wq[k], bhi(uq[k]), ay);
    }
  }
  for (; q < nl; ++q) {
    const int   sq = __shfl(srcl, q, 64);
    const float wq = __shfl(wl,   q, 64);
    const u32 u = hwb[(size_t)sq * NW + lane];
    ax = fmaf(wq, blo(u), ax);
    ay = fmaf(wq, bhi(u), ay);
  }
  // rare tail: degree > 64
  for (unsigned j = s + (unsigned)nl; j < e; ++j) {
    const int src = colv[j];                 // wave-uniform
    const float w = dinv[src] * di;
    const u32 u = hwb[(size_t)src * NW + lane];
    ax = fmaf(w, blo(u), ax);
    ay = fmaf(w, bhi(u), ay);
  }

  const float2 b = *(const float2*)&bias[lane * 2];
  ax += b.x; ay += b.y;
  ax = ax > 0.f ? ax : 0.f;
  ay = ay > 0.f ? ay : 0.f;
  hob[(size_t)wid * NW + lane] = bpack(ax, ay);
}

// ---------------- Head GEMV: out = h @ head_W + head_b ----------------

__global__ __launch_bounds__(256) void k_head(const u32* __restrict__ hb,
                                              const float* __restrict__ hW,
                                              const float* __restrict__ hbv,
                                              float* __restrict__ out) {
  const int widt = (blockIdx.x * 256 + threadIdx.x) >> 6;
  if (widt >= NN) return;
  const int wid = __builtin_amdgcn_readfirstlane(widt);
  const int lane = threadIdx.x & 63;
  const u32 v = hb[(size_t)wid * NW + lane];
  const float2 w = *(const float2*)&hW[lane * 2];
  float sum = blo(v) * w.x + bhi(v) * w.y;
#pragma unroll
  for (int off = 32; off > 0; off >>= 1) sum += __shfl_down(sum, off, 64);
  if (lane == 0) out[wid] = sum + hbv[0];
}

// ---------------- launch ----------------

extern "C" void kernel_launch(void* const* d_in, const int* in_sizes, int n_in,
                              void* d_out, int out_size, void* d_ws, size_t ws_size,
                              hipStream_t stream) {
  const float* x   = (const float*)d_in[0];
  const int*   ei  = (const int*)d_in[1];
  const float* Ws  = (const float*)d_in[2];
  const float* bs  = (const float*)d_in[3];
  const float* hW  = (const float*)d_in[4];
  const float* hb  = (const float*)d_in[5];
  float* out = (float*)d_out;

  char* w = (char*)d_ws;
  u32*      bufA    = (u32*)w;      w += (size_t)NN * NW * 4;        // 25.6 MB (h)
  u32*      bufB    = (u32*)w;      w += (size_t)NN * NW * 4;        // 25.6 MB (hw)
  int*      colv    = (int*)w;      w += (size_t)NE * 4;             // 6.4 MB
  u32*      ebuf    = (u32*)w;      w += (size_t)NE * 4;             // 6.4 MB
  u32*      hist    = (u32*)w;      w += (size_t)NBK * NCH * 4;      // 400 KB
  u32*      Wtb     = (u32*)w;      w += (size_t)NL * 128 * 64 * 4;  // 96 KB
  unsigned* rowptr  = (unsigned*)w; w += (size_t)(NN + 16) * 4;
  float*    dinv    = (float*)w;    w += (size_t)NN * 4;
  u32*      btot    = (u32*)w;      w += (size_t)(NBK + 8) * 4;
  u32*      bkbase  = (u32*)w;      w += (size_t)(NBK + 8) * 4;

  const int* srcv = ei;
  const int* dstv = ei + NE;

  // ---- CSR build (no global scatter) ----
  k_hist   <<<NCH, 256, 0, stream>>>(dstv, hist);
  k_btot   <<<NBK, 256, 0, stream>>>(hist, btot);
  k_bscan  <<<1,   512, 0, stream>>>(btot, bkbase);
  k_cscan  <<<NBK, 256, 0, stream>>>(bkbase, hist);
  k_scatter<<<NCH, 256, 0, stream>>>(srcv, dstv, hist, ebuf);
  k_build  <<<NBK, 256, 0, stream>>>(ebuf, bkbase, colv, rowptr, dinv);

  // ---- feature/weight conversion ----
  k_cvt <<<(NN * NW + 255) / 256, 256, 0, stream>>>(x, bufA);
  k_wcvt<<<(NL * 128 * 64 + 255) / 256, 256, 0, stream>>>(Ws, Wtb);

  // ---- layers ----
  for (int l = 0; l < NL; ++l) {
    k_gemm<<<(NN + 127) / 128, 512, 0, stream>>>(bufA, Wtb + (size_t)l * 128 * 64, bufB);
    k_agg <<<(NN + 3) / 4, 256, 0, stream>>>(bufB, colv, rowptr, dinv,
                                             bs + (size_t)l * D, bufA);
  }

  k_head<<<(NN + 3) / 4, 256, 0, stream>>>(bufA, hW, hb, out);
}

// Round 9
// 287.645 us; speedup vs baseline: 1.6529x; 1.0819x over previous
//
#include <hip/hip_runtime.h>
#include <math.h>

#define NN 100000     // nodes
#define NE 1600000    // edges
#define D  128        // feature dim
#define NW 64         // u32 words per row (D/2 packed bf16x2)
#define NL 3          // layers
#define NCH 256       // edge chunks (NE % NCH == 0 -> CH = 6250)
#define CH  (NE / NCH)
#define NBK 391       // dst buckets: dst >> 8, (NN+255)>>8
#define CAP 6016      // LDS colv staging capacity per bucket (mean 4096, sd 64)

typedef unsigned int u32;
typedef __attribute__((ext_vector_type(8))) short bf16x8;
typedef __attribute__((ext_vector_type(4))) float f32x4;

// ---- packed bf16x2 helpers (RNE) ----
__device__ inline float blo(u32 v) { return __uint_as_float(v << 16); }
__device__ inline float bhi(u32 v) { return __uint_as_float(v & 0xffff0000u); }
__device__ inline u32 bpack(float x, float y) {
  u32 xb = __float_as_uint(x), yb = __float_as_uint(y);
  xb = (xb + 0x7fffu + ((xb >> 16) & 1u)) >> 16;
  yb = (yb + 0x7fffu + ((yb >> 16) & 1u)) & 0xffff0000u;
  return xb | yb;
}

// ================= bucketed CSR build (no global scatter) =================

// Phase A: per-chunk histogram of dst>>8 into LDS, coalesced dump.
__global__ __launch_bounds__(256) void k_hist(const int* __restrict__ dstv,
                                              u32* __restrict__ hist) {
  __shared__ u32 h[NBK];
  const int t = threadIdx.x, c = blockIdx.x;
  for (int b = t; b < NBK; b += 256) h[b] = 0u;
  __syncthreads();
  const int base = c * CH;
  for (int i = t; i < CH; i += 256)
    atomicAdd(&h[dstv[base + i] >> 8], 1u);
  __syncthreads();
  for (int b = t; b < NBK; b += 256) hist[b * NCH + c] = h[b];
}

// Phase B1: per-bucket totals (one block per bucket, coalesced row read).
__global__ __launch_bounds__(256) void k_btot(const u32* __restrict__ hist,
                                              u32* __restrict__ btot) {
  __shared__ u32 s[256];
  const int b = blockIdx.x, t = threadIdx.x;
  s[t] = hist[b * NCH + t];
  __syncthreads();
  for (int off = 128; off > 0; off >>= 1) {
    if (t < off) s[t] += s[t + off];
    __syncthreads();
  }
  if (t == 0) btot[b] = s[0];
}

// Phase B2: exclusive scan of 391 bucket totals.
__global__ __launch_bounds__(512) void k_bscan(const u32* __restrict__ btot,
                                               u32* __restrict__ bkbase) {
  __shared__ u32 s[512];
  const int t = threadIdx.x;
  const u32 v = (t < NBK) ? btot[t] : 0u;
  s[t] = v;
  __syncthreads();
  for (int off = 1; off < 512; off <<= 1) {
    const u32 x = (t >= off) ? s[t - off] : 0u;
    __syncthreads();
    s[t] += x;
    __syncthreads();
  }
  if (t < NBK) bkbase[t] = s[t] - v;
  if (t == 0) bkbase[NBK] = NE;
}

// Phase B3: per-bucket exclusive scan over chunk counts -> absolute offsets.
__global__ __launch_bounds__(256) void k_cscan(const u32* __restrict__ bkbase,
                                               u32* __restrict__ hist) {
  __shared__ u32 s[256];
  const int b = blockIdx.x, t = threadIdx.x;
  const u32 v = hist[b * NCH + t];
  s[t] = v;
  __syncthreads();
  for (int off = 1; off < 256; off <<= 1) {
    const u32 x = (t >= off) ? s[t - off] : 0u;
    __syncthreads();
    s[t] += x;
    __syncthreads();
  }
  hist[b * NCH + t] = bkbase[b] + s[t] - v;
}

// Phase C: scatter edges into bucket-major order. LDS cursors -> each block's
// writes per bucket form a contiguous ~64B run (no line ping-pong).
__global__ __launch_bounds__(256) void k_scatter(const int* __restrict__ srcv,
                                                 const int* __restrict__ dstv,
                                                 const u32* __restrict__ off,
                                                 u32* __restrict__ ebuf) {
  __shared__ u32 cur[NBK];
  const int t = threadIdx.x, c = blockIdx.x;
  for (int b = t; b < NBK; b += 256) cur[b] = off[b * NCH + c];
  __syncthreads();
  const int base = c * CH;
  for (int i = t; i < CH; i += 256) {
    const int d = dstv[base + i], s = srcv[base + i];
    const u32 p = atomicAdd(&cur[d >> 8], 1u);
    ebuf[p] = (u32)s | ((u32)(d & 255) << 17);   // src:17b | dst_local:8b
  }
}

// Phase D: one block per bucket. LDS node-histogram + scan -> rowptr + dinv;
// LDS scatter -> coalesced colv write.
__global__ __launch_bounds__(256) void k_build(const u32* __restrict__ ebuf,
                                               const u32* __restrict__ bkbase,
                                               int* __restrict__ colv,
                                               unsigned* __restrict__ rowptr,
                                               float* __restrict__ dinv) {
  __shared__ u32 loc[256];
  __shared__ u32 curn[256];
  __shared__ u32 hl[256];
  __shared__ u32 cbuf[CAP];
  const int b = blockIdx.x, t = threadIdx.x;
  const u32 e0 = bkbase[b], e1 = bkbase[b + 1];
  const int cnt = (int)(e1 - e0);
  const int node = (b << 8) + t;

  hl[t] = 0u;
  __syncthreads();
  for (int i = t; i < cnt; i += 256)
    atomicAdd(&hl[(ebuf[e0 + i] >> 17) & 255u], 1u);
  __syncthreads();
  const u32 v = hl[t];
  loc[t] = v;
  __syncthreads();
  for (int off = 1; off < 256; off <<= 1) {
    const u32 x = (t >= off) ? loc[t - off] : 0u;
    __syncthreads();
    loc[t] += x;
    __syncthreads();
  }
  const u32 excl = loc[t] - v;
  if (node < NN) {
    rowptr[node] = e0 + excl;
    dinv[node] = rsqrtf((float)(v + 1u));     // in-degree + self-loop
  }
  if (b == NBK - 1 && t == 0) rowptr[NN] = NE;
  curn[t] = excl;
  __syncthreads();

  if (cnt <= CAP) {
    for (int i = t; i < cnt; i += 256) {
      const u32 e = ebuf[e0 + i];
      const u32 p = atomicAdd(&curn[(e >> 17) & 255u], 1u);
      cbuf[p] = e & 0x1FFFFu;
    }
    __syncthreads();
    for (int i = t; i < cnt; i += 256) colv[e0 + i] = (int)cbuf[i];
  } else {      // statistically unreachable safety net
    for (int i = t; i < cnt; i += 256) {
      const u32 e = ebuf[e0 + i];
      const u32 p = atomicAdd(&curn[(e >> 17) & 255u], 1u);
      colv[e0 + p] = (int)(e & 0x1FFFFu);
    }
  }
}

// ---------------- x -> packed bf16 ----------------

__global__ __launch_bounds__(256) void k_cvt(const float* __restrict__ x,
                                             u32* __restrict__ xb) {
  int i = blockIdx.x * 256 + threadIdx.x;
  if (i < NN * NW) {
    const float2 v = *(const float2*)&x[(size_t)i * 2];
    xb[i] = bpack(v.x, v.y);
  }
}

// ---------------- W (f32 [k][n]) -> bf16 W^T [n][k], packed u32 ----------------

__global__ __launch_bounds__(256) void k_wcvt(const float* __restrict__ Ws,
                                              u32* __restrict__ Wtb) {
  int i = blockIdx.x * 256 + threadIdx.x;   // l*8192 + n*64 + kw
  if (i >= NL * 128 * 64) return;
  const int l = i >> 13, rem = i & 8191, n = rem >> 6, kw = rem & 63;
  const float* Wp = Ws + l * (D * D);
  Wtb[i] = bpack(Wp[(2 * kw) * D + n], Wp[(2 * kw + 1) * D + n]);
}

// ---------------- GEMM: hw = h @ W  (bf16 MFMA, W^T in swizzled LDS) ----------

__global__ __launch_bounds__(512, 4) void k_gemm(const u32* __restrict__ Ab,
                                                 const u32* __restrict__ Wtb,
                                                 u32* __restrict__ Bb) {
  __shared__ u32 Wl[128 * 64];   // 32 KB
  const int t = threadIdx.x;
#pragma unroll
  for (int i = 0; i < 4; ++i) {
    const int idx = (t + i * 512) * 4;          // u32 index of a 16B chunk
    const uint4 v = *(const uint4*)(Wtb + idx);
    const int byte = idx * 4;
    const int sw = byte ^ (((byte >> 8) & 7) << 4);
    *(uint4*)((char*)Wl + sw) = v;
  }
  __syncthreads();

  const int wave = t >> 6, lane = t & 63;
  const int hi = lane >> 4;                     // 0..3
  const int lo = lane & 15;
  int row = blockIdx.x * 128 + wave * 16 + lo;
  const int rowc = row < NN ? row : NN - 1;     // clamp reads, guard writes

  bf16x8 af[4];
#pragma unroll
  for (int ks = 0; ks < 4; ++ks)
    af[ks] = *(const bf16x8*)(Ab + (size_t)rowc * NW + ks * 16 + hi * 4);

  f32x4 acc[8];
#pragma unroll
  for (int ct = 0; ct < 8; ++ct) acc[ct] = (f32x4){0.f, 0.f, 0.f, 0.f};

#pragma unroll
  for (int ks = 0; ks < 4; ++ks) {
#pragma unroll
    for (int ct = 0; ct < 8; ++ct) {
      const int n = ct * 16 + lo;
      const int addr = (n * 256 + ks * 64 + hi * 16) ^ ((n & 7) << 4);
      const bf16x8 bf = *(const bf16x8*)((const char*)Wl + addr);
      acc[ct] = __builtin_amdgcn_mfma_f32_16x16x32_bf16(af[ks], bf, acc[ct], 0, 0, 0);
    }
  }

  const int rbase = blockIdx.x * 128 + wave * 16 + hi * 4;
  const bool even = (lane & 1) == 0;
  const int wcol = lo >> 1;                     // word index within ct's 8
#pragma unroll
  for (int ct = 0; ct < 8; ++ct) {
    float p0 = __shfl_xor(acc[ct][0], 1, 64);
    float p1 = __shfl_xor(acc[ct][1], 1, 64);
    float p2 = __shfl_xor(acc[ct][2], 1, 64);
    float p3 = __shfl_xor(acc[ct][3], 1, 64);
    const u32 wA = even ? bpack(acc[ct][0], p0) : bpack(p2, acc[ct][2]);
    const u32 wB = even ? bpack(acc[ct][1], p1) : bpack(p3, acc[ct][3]);
    const int rA = rbase + (even ? 0 : 2);
    if (rA < NN)     Bb[(size_t)rA * NW + ct * 8 + wcol] = wA;
    if (rA + 1 < NN) Bb[(size_t)(rA + 1) * NW + ct * 8 + wcol] = wB;
  }
}

// ---------------- Aggregation core: 16-deep gather pipeline, SGPR broadcast ----
// Lanes 0..nl load (src, w); nl rounded up to x8 with zero-weight pad lanes
// (src=wid -> harmless read, fma of 0). readlane -> SGPR src/w: scalar-based
// gather addressing + 16 outstanding row gathers per wave.

__device__ __forceinline__ void agg_core(const u32* __restrict__ hwb,
                                         const int* __restrict__ colv,
                                         const unsigned* __restrict__ rowptr,
                                         const float* __restrict__ dinv,
                                         int wid, int lane,
                                         float& ax, float& ay, float& dio) {
  const float di = dinv[wid];
  dio = di;
  const u32 sv = hwb[(size_t)wid * NW + lane];
  ax = blo(sv) * di * di;
  ay = bhi(sv) * di * di;

  const unsigned s = rowptr[wid], e = rowptr[wid + 1];
  const int deg = (int)(e - s);
  const int nl = deg < 64 ? deg : 64;
  const int nlr = (nl + 7) & ~7;       // pad to x8; pad lanes have w=0

  int srcl = wid;
  float wl = 0.f;
  if (lane < nl) {
    srcl = colv[s + lane];
    wl = dinv[srcl] * di;
  }

  int q = 0;
  while (q < nlr) {
    if (q + 16 <= nlr) {
      int sq[16]; float wq[16]; u32 uq[16];
#pragma unroll
      for (int k = 0; k < 16; ++k) {
        sq[k] = __builtin_amdgcn_readlane(srcl, q + k);
        wq[k] = __uint_as_float((u32)__builtin_amdgcn_readlane((int)__float_as_uint(wl), q + k));
      }
#pragma unroll
      for (int k = 0; k < 16; ++k) uq[k] = hwb[(size_t)sq[k] * NW + lane];
#pragma unroll
      for (int k = 0; k < 16; ++k) {
        ax = fmaf(wq[k], blo(uq[k]), ax);
        ay = fmaf(wq[k], bhi(uq[k]), ay);
      }
      q += 16;
    } else {
      int sq[8]; float wq[8]; u32 uq[8];
#pragma unroll
      for (int k = 0; k < 8; ++k) {
        sq[k] = __builtin_amdgcn_readlane(srcl, q + k);
        wq[k] = __uint_as_float((u32)__builtin_amdgcn_readlane((int)__float_as_uint(wl), q + k));
      }
#pragma unroll
      for (int k = 0; k < 8; ++k) uq[k] = hwb[(size_t)sq[k] * NW + lane];
#pragma unroll
      for (int k = 0; k < 8; ++k) {
        ax = fmaf(wq[k], blo(uq[k]), ax);
        ay = fmaf(wq[k], bhi(uq[k]), ay);
      }
      q += 8;
    }
  }
  // rare tail: degree > 64
  for (unsigned j = s + (unsigned)nl; j < e; ++j) {
    const int src = colv[j];
    const float w = dinv[src] * di;
    const u32 u = hwb[(size_t)src * NW + lane];
    ax = fmaf(w, blo(u), ax);
    ay = fmaf(w, bhi(u), ay);
  }
}

__global__ __launch_bounds__(256) void k_agg(const u32* __restrict__ hwb,
                                             const int* __restrict__ colv,
                                             const unsigned* __restrict__ rowptr,
                                             const float* __restrict__ dinv,
                                             const float* __restrict__ bias,
                                             u32* __restrict__ hob) {
  const int widt = (blockIdx.x * 256 + threadIdx.x) >> 6;
  if (widt >= NN) return;
  const int wid = __builtin_amdgcn_readfirstlane(widt);
  const int lane = threadIdx.x & 63;

  float ax, ay, di;
  agg_core(hwb, colv, rowptr, dinv, wid, lane, ax, ay, di);

  const float2 b = *(const float2*)&bias[lane * 2];
  ax += b.x; ay += b.y;
  ax = ax > 0.f ? ax : 0.f;
  ay = ay > 0.f ? ay : 0.f;
  hob[(size_t)wid * NW + lane] = bpack(ax, ay);
}

// Last layer: fuse head GEMV (out = relu(agg+b) @ head_W + head_b), f32 accum,
// no bf16 store of the final hidden layer.
__global__ __launch_bounds__(256) void k_agg_head(const u32* __restrict__ hwb,
                                                  const int* __restrict__ colv,
                                                  const unsigned* __restrict__ rowptr,
                                                  const float* __restrict__ dinv,
                                                  const float* __restrict__ bias,
                                                  const float* __restrict__ hW,
                                                  const float* __restrict__ hbv,
                                                  float* __restrict__ out) {
  const int widt = (blockIdx.x * 256 + threadIdx.x) >> 6;
  if (widt >= NN) return;
  const int wid = __builtin_amdgcn_readfirstlane(widt);
  const int lane = threadIdx.x & 63;

  float ax, ay, di;
  agg_core(hwb, colv, rowptr, dinv, wid, lane, ax, ay, di);

  const float2 b = *(const float2*)&bias[lane * 2];
  ax += b.x; ay += b.y;
  ax = ax > 0.f ? ax : 0.f;
  ay = ay > 0.f ? ay : 0.f;

  const float2 w = *(const float2*)&hW[lane * 2];
  float sum = ax * w.x + ay * w.y;
#pragma unroll
  for (int off = 32; off > 0; off >>= 1) sum += __shfl_down(sum, off, 64);
  if (lane == 0) out[wid] = sum + hbv[0];
}

// ---------------- launch ----------------

extern "C" void kernel_launch(void* const* d_in, const int* in_sizes, int n_in,
                              void* d_out, int out_size, void* d_ws, size_t ws_size,
                              hipStream_t stream) {
  const float* x   = (const float*)d_in[0];
  const int*   ei  = (const int*)d_in[1];
  const float* Ws  = (const float*)d_in[2];
  const float* bs  = (const float*)d_in[3];
  const float* hW  = (const float*)d_in[4];
  const float* hb  = (const float*)d_in[5];
  float* out = (float*)d_out;

  char* w = (char*)d_ws;
  u32*      bufA    = (u32*)w;      w += (size_t)NN * NW * 4;        // 25.6 MB (h)
  u32*      bufB    = (u32*)w;      w += (size_t)NN * NW * 4;        // 25.6 MB (hw)
  int*      colv    = (int*)w;      w += (size_t)NE * 4;             // 6.4 MB
  u32*      ebuf    = (u32*)w;      w += (size_t)NE * 4;             // 6.4 MB
  u32*      hist    = (u32*)w;      w += (size_t)NBK * NCH * 4;      // 400 KB
  u32*      Wtb     = (u32*)w;      w += (size_t)NL * 128 * 64 * 4;  // 96 KB
  unsigned* rowptr  = (unsigned*)w; w += (size_t)(NN + 16) * 4;
  float*    dinv    = (float*)w;    w += (size_t)NN * 4;
  u32*      btot    = (u32*)w;      w += (size_t)(NBK + 8) * 4;
  u32*      bkbase  = (u32*)w;      w += (size_t)(NBK + 8) * 4;

  const int* srcv = ei;
  const int* dstv = ei + NE;

  // ---- CSR build (no global scatter) ----
  k_hist   <<<NCH, 256, 0, stream>>>(dstv, hist);
  k_btot   <<<NBK, 256, 0, stream>>>(hist, btot);
  k_bscan  <<<1,   512, 0, stream>>>(btot, bkbase);
  k_cscan  <<<NBK, 256, 0, stream>>>(bkbase, hist);
  k_scatter<<<NCH, 256, 0, stream>>>(srcv, dstv, hist, ebuf);
  k_build  <<<NBK, 256, 0, stream>>>(ebuf, bkbase, colv, rowptr, dinv);

  // ---- feature/weight conversion ----
  k_cvt <<<(NN * NW + 255) / 256, 256, 0, stream>>>(x, bufA);
  k_wcvt<<<(NL * 128 * 64 + 255) / 256, 256, 0, stream>>>(Ws, Wtb);

  // ---- layers ----
  for (int l = 0; l < NL; ++l) {
    k_gemm<<<(NN + 127) / 128, 512, 0, stream>>>(bufA, Wtb + (size_t)l * 128 * 64, bufB);
    if (l < NL - 1) {
      k_agg<<<(NN + 3) / 4, 256, 0, stream>>>(bufB, colv, rowptr, dinv,
                                              bs + (size_t)l * D, bufA);
    } else {
      k_agg_head<<<(NN + 3) / 4, 256, 0, stream>>>(bufB, colv, rowptr, dinv,
                                                   bs + (size_t)l * D, hW, hb, out);
    }
  }
}